// Round 10
// baseline (454.532 us; speedup 1.0000x reference)
//
#include <hip/hip_runtime.h>
#include <math.h>

// Problem dims
#define B_ 4
#define L_ 512
#define MROWS 2048
#define D_MODEL 384
#define N_LAYER 4
#define D_INNER 768
#define N_STATE 16
#define DT_RANK 24
#define D_CONV 4
#define VOCAB 1544
#define FEAT 1536
#define XPROJ_N 56
#define NCH 16              // scan chunks per batch (L/32)
#define SCH 32              // scan chunk length
#define DG 2                // d-channels per scan block

typedef __attribute__((ext_vector_type(8))) short short8;
typedef __attribute__((ext_vector_type(4))) float floatx4;

__device__ __forceinline__ float softplus_f(float x) { return x > 20.f ? x : log1pf(expf(x)); }
__device__ __forceinline__ float silu_f(float x) { return x / (1.f + __expf(-x)); }

// f32 -> bf16 (RNE), two packed into one u32
__device__ __forceinline__ unsigned pack2bf(float x, float y) {
    unsigned ux = __float_as_uint(x); ux = (ux + 0x7FFFu + ((ux >> 16) & 1u)) >> 16;
    unsigned uy = __float_as_uint(y); uy = (uy + 0x7FFFu + ((uy >> 16) & 1u)) >> 16;
    return ux | (uy << 16);
}

// DPP row-rotate add: x + (x ror N within each 16-lane row). After ror
// 8,4,2,1 every lane holds the full 16-sum.
template <int CTRL>
__device__ __forceinline__ float dpp_radd(float x) {
    int r = __builtin_amdgcn_update_dpp(0, __float_as_int(x), CTRL, 0xf, 0xf, true);
    return x + __int_as_float(r);
}

// Wave-local LDS fence: producer and consumer are the SAME wave (cross-lane
// ok) -- s_waitcnt makes the wave's own ds_writes visible, wave_barrier pins
// ordering. Replaces __syncthreads where no cross-wave data flows.
__device__ __forceinline__ void wave_lds_fence() {
    asm volatile("s_waitcnt lgkmcnt(0)" ::: "memory");
    __builtin_amdgcn_wave_barrier();
}

__device__ __forceinline__ short8 ld8h_guard(const short* __restrict__ p, int k, int ke) {
    if (k + 7 < ke) return *(const short8*)(p + k);
    short8 r = {0, 0, 0, 0, 0, 0, 0, 0};
#pragma unroll
    for (int j = 0; j < 8; ++j)
        if (k + j < ke) r[j] = p[k + j];
    return r;
}

// ---------------------------------------------------------------------------
// One-shot weight/input cast f32 -> bf16 + grid-stride zeroing of atomic dsts.
// ---------------------------------------------------------------------------
struct CastDesc {
    const float* src[6];
    short*       dst[6];
    unsigned     cum[6];   // exclusive prefix ends, in float4 units
};

__global__ __launch_bounds__(256) void cast_w_k(CastDesc cd, unsigned total4,
                                                float4* __restrict__ zb, unsigned z4)
{
    unsigned i = blockIdx.x * 256 + threadIdx.x;
    if (i < total4) {
        int s = 0;
#pragma unroll
        for (int j = 0; j < 5; ++j)
            if (i >= cd.cum[j] && s == j) s = j + 1;
        unsigned off = i - (s ? cd.cum[s - 1] : 0u);
        float4 v = ((const float4*)cd.src[s])[off];
        uint2 pk;
        pk.x = pack2bf(v.x, v.y);
        pk.y = pack2bf(v.z, v.w);
        ((uint2*)cd.dst[s])[off] = pk;
    } else {
        unsigned zi = i - total4;
        if (zi < z4) zb[zi] = make_float4(0.f, 0.f, 0.f, 0.f);
    }
}

// ---------------------------------------------------------------------------
// RMSNorm + weight scale + bf16 cast, one pass.  8 lanes per row.
// ---------------------------------------------------------------------------
__global__ __launch_bounds__(256) void rmsnorm_cast_k(
    const float* __restrict__ x, const float* __restrict__ nw,
    unsigned* __restrict__ outp)
{
    const int idx = blockIdx.x * 256 + threadIdx.x;
    const int row = idx >> 3, q = idx & 7;
    const float* xr = x + (size_t)row * D_MODEL + q * 48;
    float4 v[12];
    float s = 0.f;
#pragma unroll
    for (int i = 0; i < 12; ++i) {
        v[i] = *(const float4*)(xr + i * 4);
        s += v[i].x * v[i].x + v[i].y * v[i].y + v[i].z * v[i].z + v[i].w * v[i].w;
    }
    s += __shfl_xor(s, 1, 64);
    s += __shfl_xor(s, 2, 64);
    s += __shfl_xor(s, 4, 64);
    const float sc = rsqrtf(s / (float)D_MODEL + 1e-5f);
    unsigned* op = outp + ((size_t)row * D_MODEL + q * 48) / 2;
#pragma unroll
    for (int i = 0; i < 12; ++i) {
        float4 wv = *(const float4*)(nw + q * 48 + i * 4);
        op[i * 2]     = pack2bf(v[i].x * (sc * wv.x), v[i].y * (sc * wv.y));
        op[i * 2 + 1] = pack2bf(v[i].z * (sc * wv.z), v[i].w * (sc * wv.w));
    }
}

// ---------------------------------------------------------------------------
// MFMA bf16 GEMM: C[m,n] (+)= sum_k A[m,k]*W[n,k].  A and W pre-cast bf16.
// Pipelined K-loop: stage(k+1) -> prefetch(k+2) -> MFMA(k) -> barrier.
// EPI: 0 none, 1 +bias(z==0 if ATOMIC), 2 softplus+bias.
// ---------------------------------------------------------------------------
#define ASTR 40

template <int EPI, bool ATOMIC, bool NG>
__global__ __launch_bounds__(256) void mfma_gemm(
    const short* __restrict__ Abf,
    const short* __restrict__ Wb,
    const float* __restrict__ bias,
    float* __restrict__ C, int M, int N, int K, int lda, int ldc, int KC)
{
    __shared__ short As[2][64 * ASTR];
    __shared__ short Ws[2][64 * ASTR];

    const int t  = threadIdx.x;
    const int m0 = blockIdx.y * 64;
    const int n0 = blockIdx.x * 64;
    const int ks = blockIdx.z * KC;
    const int ke = min(K, ks + KC);

    const int srow = t >> 2;           // 0..63
    const int sseg = (t & 3) * 8;      // 0,8,16,24

    short8 ra8, rw8;

    auto prefetch = [&](int k0) {
        ra8 = ld8h_guard(Abf + (size_t)(m0 + srow) * lda, k0 + sseg, ke);
        if (!NG || (n0 + srow) < N) {
            rw8 = ld8h_guard(Wb + (size_t)(n0 + srow) * (size_t)K, k0 + sseg, ke);
        } else {
            rw8 = (short8){0, 0, 0, 0, 0, 0, 0, 0};
        }
    };

    auto stage = [&](int p) {
        *(short8*)&As[p][srow * ASTR + sseg] = ra8;
        *(short8*)&Ws[p][srow * ASTR + sseg] = rw8;
    };

    prefetch(ks);
    stage(0);
    if (ks + 32 < ke) prefetch(ks + 32);   // loads for iter 2 in flight across barrier
    __syncthreads();

    floatx4 acc[2][2];
#pragma unroll
    for (int i = 0; i < 2; ++i)
#pragma unroll
        for (int j = 0; j < 2; ++j) acc[i][j] = (floatx4){0.f, 0.f, 0.f, 0.f};

    const int w    = t >> 6;
    const int lane = t & 63;
    const int quad = lane >> 4;
    const int lm   = lane & 15;
    const int aoff = ((w >> 1) * 32 + lm) * ASTR + quad * 8;
    const int boff = ((w & 1) * 32 + lm) * ASTR + quad * 8;

    int p = 0;
    for (int k0 = ks; k0 < ke; k0 += 32) {
        const bool more = (k0 + 32 < ke);
        if (more) {
            stage(p ^ 1);                       // consumes loads issued 1 iter ago
            if (k0 + 64 < ke) prefetch(k0 + 64); // issue 2 iters ahead
        }
        short8 a0 = *(const short8*)&As[p][aoff];
        short8 a1 = *(const short8*)&As[p][aoff + 16 * ASTR];
        short8 b0 = *(const short8*)&Ws[p][boff];
        short8 b1 = *(const short8*)&Ws[p][boff + 16 * ASTR];
        acc[0][0] = __builtin_amdgcn_mfma_f32_16x16x32_bf16(a0, b0, acc[0][0], 0, 0, 0);
        acc[0][1] = __builtin_amdgcn_mfma_f32_16x16x32_bf16(a0, b1, acc[0][1], 0, 0, 0);
        acc[1][0] = __builtin_amdgcn_mfma_f32_16x16x32_bf16(a1, b0, acc[1][0], 0, 0, 0);
        acc[1][1] = __builtin_amdgcn_mfma_f32_16x16x32_bf16(a1, b1, acc[1][1], 0, 0, 0);
        if (more) {
            __syncthreads();
            p ^= 1;
        }
    }

    const int rbase = m0 + (w >> 1) * 32 + quad * 4;
    const int cbase = n0 + (w & 1) * 32 + lm;
#pragma unroll
    for (int mt = 0; mt < 2; ++mt)
#pragma unroll
        for (int nt = 0; nt < 2; ++nt) {
            const int gc = cbase + nt * 16;
            if (NG && gc >= N) continue;
#pragma unroll
            for (int r = 0; r < 4; ++r) {
                const size_t gr = rbase + mt * 16 + r;
                float v = acc[mt][nt][r];
                if (ATOMIC) {
                    if (EPI == 1 && blockIdx.z == 0) v += bias[gc];
                    atomicAdd(&C[gr * ldc + gc], v);
                } else {
                    if (EPI == 1) v += bias[gc];
                    if (EPI == 2) v = softplus_f(v + bias[gc]);
                    C[gr * ldc + gc] = v;
                }
            }
        }
}

// ---------------------------------------------------------------------------
// Depthwise causal conv (width 4) + bias + SiLU; writes u (f32) and u_bf.
// (r6 form -- coalesced: consecutive threads = consecutive d within a row.
// r7/r9 fusion attempts both lost to this plain version.)
// ---------------------------------------------------------------------------
__global__ __launch_bounds__(256) void conv_silu_k(
    const float* __restrict__ xz, const float* __restrict__ w,
    const float* __restrict__ cb, float* __restrict__ u, short* __restrict__ ubf)
{
    int idx = blockIdx.x * 256 + threadIdx.x;
    if (idx >= MROWS * (D_INNER / 4)) return;
    int dq = idx % (D_INNER / 4);
    int m  = idx / (D_INNER / 4);
    int d0 = dq * 4;
    int b = m / L_, l = m % L_;
    float4 wq[4];
#pragma unroll
    for (int j = 0; j < 4; ++j) wq[j] = *(const float4*)(w + (d0 + j) * D_CONV);
    float acc[4];
#pragma unroll
    for (int j = 0; j < 4; ++j) acc[j] = cb[d0 + j];
#pragma unroll
    for (int tt = 0; tt < 4; ++tt) {
        int ll = l - 3 + tt;
        if (ll >= 0) {
            float4 xv = *(const float4*)(xz + (size_t)(b * L_ + ll) * (2 * D_INNER) + d0);
            acc[0] = fmaf(xv.x, ((const float*)&wq[0])[tt], acc[0]);
            acc[1] = fmaf(xv.y, ((const float*)&wq[1])[tt], acc[1]);
            acc[2] = fmaf(xv.z, ((const float*)&wq[2])[tt], acc[2]);
            acc[3] = fmaf(xv.w, ((const float*)&wq[3])[tt], acc[3]);
        }
    }
    float4 o = make_float4(silu_f(acc[0]), silu_f(acc[1]), silu_f(acc[2]), silu_f(acc[3]));
    *(float4*)(u + (size_t)m * D_INNER + d0) = o;
    uint2 pk;
    pk.x = pack2bf(o.x, o.y);
    pk.y = pack2bf(o.z, o.w);
    *(uint2*)(ubf + (size_t)m * D_INNER + d0) = pk;
}

// ---------------------------------------------------------------------------
// Fused selective scan (exact r6 form -- best measured; r8's register-carry
// variant cost occupancy and regressed).  Carry-folded two-pass:
//   phase 0: row-task dt-proj (each thread one row, both channels), {delta,u}
//            packed float2 in LDS, early xz gate load
//   pass 1 : P/H only, no reduce; P = exp(Av*sum(dv))
//   barrier; pass-2 group-0 B/C loads issued before it
//   carry  : fixed-unroll masked fold (15 batched LDS loads)
//   pass 2 : full recurrence from h=hs (B/C reload, 8-deep prefetch)
//   phase C: gate + bf16 emit
// ---------------------------------------------------------------------------
__global__ __launch_bounds__(512, 4) void scan_fused_k(
    const float* __restrict__ xdbl, const float* __restrict__ u,
    const float* __restrict__ xz,
    const float* __restrict__ dtW, const float* __restrict__ dtb,
    const float* __restrict__ A_log, const float* __restrict__ Dp,
    short* __restrict__ ybf)
{
    __shared__ __align__(16) float2 sdu[NCH][SCH][DG];     // {delta,u} 8KB
    __shared__ __align__(16) float  sy[NCH][SCH][DG];      // 4KB
    __shared__ __align__(16) float2 sPH[NCH][DG][16];      // {P,H} 4KB

    const int t  = threadIdx.x;
    const int w  = t >> 6;          // wave 0..7
    const int l  = t & 63;
    const int ch = l >> 5;          // 0..1 -> which of the wave's two chunks
    const int c  = w * 2 + ch;      // chunk 0..15
    const int dl = (l >> 4) & 1;    // channel within block
    const int n  = l & 15;          // state index
    // XCD-chunked swizzle (bijective, 384 = 8 * 48): adjacent d-groups share
    // cache lines of u/xz/ybf -> keep them on one XCD (r1: FETCH 51->8MB).
    const int bx  = blockIdx.x;
    const int dgi = (bx & 7) * (D_INNER / DG / 8) + (bx >> 3);
    const int d0 = dgi * DG;
    const int d  = d0 + dl;
    const int b  = blockIdx.y;

    // row-task mapping (each thread owns one global row)
    const int tc = t >> 5, tj = t & 31;          // tc in {2w, 2w+1} -> wave-private
    const size_t trow = (size_t)b * L_ + t;

    // ---- phase 0: wave-private staging ----
    // early-issue phase-C gate load (consumed ~3000cy later)
    float2 rv  = *(const float2*)(xz + trow * (2 * D_INNER) + D_INNER + d0);
    float2 uv2 = *(const float2*)(u + trow * D_INNER + d0);

    // delta for BOTH channels of this thread's row; dtW/dtb are block-uniform
    {
        const float* wd = dtW + (size_t)d0 * DT_RANK;
        const float* xr = xdbl + trow * XPROJ_N;
        float acc0 = dtb[d0];
        float acc1 = dtb[d0 + 1];
#pragma unroll
        for (int q = 0; q < 6; ++q) {
            float4 xv = *(const float4*)(xr + q * 4);
            float4 w0 = *(const float4*)(wd + q * 4);
            float4 w1 = *(const float4*)(wd + DT_RANK + q * 4);
            acc0 = fmaf(xv.x, w0.x, acc0); acc0 = fmaf(xv.y, w0.y, acc0);
            acc0 = fmaf(xv.z, w0.z, acc0); acc0 = fmaf(xv.w, w0.w, acc0);
            acc1 = fmaf(xv.x, w1.x, acc1); acc1 = fmaf(xv.y, w1.y, acc1);
            acc1 = fmaf(xv.z, w1.z, acc1); acc1 = fmaf(xv.w, w1.w, acc1);
        }
        float4 pk = make_float4(softplus_f(acc0), uv2.x, softplus_f(acc1), uv2.y);
        *(float4*)&sdu[tc][tj][0] = pk;   // one ds_write_b128
    }
    wave_lds_fence();   // sdu for chunks {2w,2w+1} produced+consumed by wave w

    const float Av = -expf(A_log[d * N_STATE + n]);
    const float Dd = Dp[d];
    const float* xbn = xdbl + ((size_t)b * L_ + c * SCH) * XPROJ_N + DT_RANK + n;

    // ---- pass 1: chunk-local end-state H and decay product P (no reduce) ----
    {
        float h = 0.f, sdv = 0.f;
        float rB[8];
#pragma unroll
        for (int q = 0; q < 8; ++q) rB[q] = xbn[q * XPROJ_N];
#pragma unroll
        for (int g = 0; g < SCH / 8; ++g) {
            float nB[8];
            if (g + 1 < SCH / 8) {
#pragma unroll
                for (int q = 0; q < 8; ++q) nB[q] = xbn[(g * 8 + 8 + q) * XPROJ_N];
            }
#pragma unroll
            for (int q = 0; q < 8; ++q) {
                const int j = g * 8 + q;
                float2 du = *(const float2*)&sdu[c][j][dl];
                float e  = __expf(du.x * Av);
                h = fmaf(e, h, du.x * du.y * rB[q]);
                sdv += du.x;
            }
#pragma unroll
            for (int q = 0; q < 8; ++q) rB[q] = nB[q];
        }
        float2 ph;
        ph.x = __expf(sdv * Av);   // prod of exps = exp of sum
        ph.y = h;
        *(float2*)&sPH[c][dl][n] = ph;
    }

    // issue pass-2 group-0 B/C loads BEFORE the barrier (latency cover)
    float rB[8], rC[8];
#pragma unroll
    for (int q = 0; q < 8; ++q) {
        rB[q] = xbn[q * XPROJ_N];
        rC[q] = xbn[q * XPROJ_N + N_STATE];
    }
    __syncthreads();    // the only cross-wave exchange (sPH)

    // ---- carry-in: fixed-unroll masked fold (all 15 loads batch) ----
    float hs = 0.f;
#pragma unroll
    for (int s = 0; s < NCH - 1; ++s) {
        float2 ph = *(const float2*)&sPH[s][dl][n];
        const bool m = s < c;
        hs = fmaf(m ? ph.x : 1.f, hs, m ? ph.y : 0.f);
    }

    // ---- pass 2: full recurrence from h=hs; y is final directly ----
    {
        float h = hs;
#pragma unroll
        for (int g = 0; g < SCH / 8; ++g) {
            float nB[8], nC[8];
            if (g + 1 < SCH / 8) {
#pragma unroll
                for (int q = 0; q < 8; ++q) {
                    nB[q] = xbn[(g * 8 + 8 + q) * XPROJ_N];
                    nC[q] = xbn[(g * 8 + 8 + q) * XPROJ_N + N_STATE];
                }
            }
#pragma unroll
            for (int q = 0; q < 8; ++q) {
                const int j = g * 8 + q;
                float2 du = *(const float2*)&sdu[c][j][dl];
                float e  = __expf(du.x * Av);
                h = fmaf(e, h, du.x * du.y * rB[q]);
                float p = h * rC[q];
                p = dpp_radd<0x128>(p);
                p = dpp_radd<0x124>(p);
                p = dpp_radd<0x122>(p);
                p = dpp_radd<0x121>(p);
                if (n == 0) sy[c][j][dl] = fmaf(du.y, Dd, p);
            }
#pragma unroll
            for (int q = 0; q < 8; ++q) { rB[q] = nB[q]; rC[q] = nC[q]; }
        }
    }
    wave_lds_fence();   // sy for chunks {2w,2w+1} is wave-private

    // ---- phase C: gate with silu(res) and emit bf16 ----
    {
        float2 yv = *(const float2*)&sy[tc][tj][0];
        float o0 = yv.x * silu_f(rv.x);
        float o1 = yv.y * silu_f(rv.y);
        *(unsigned*)(ybf + trow * D_INNER + d0) = pack2bf(o0, o1);
    }
}

// ---------------------------------------------------------------------------
extern "C" void kernel_launch(void* const* d_in, const int* in_sizes, int n_in,
                              void* d_out, int out_size, void* d_ws, size_t ws_size,
                              hipStream_t stream)
{
    const float* input_ids = (const float*)d_in[0];
    const float* fc_W      = (const float*)d_in[1];
    const float* fc_b      = (const float*)d_in[2];
    const float* in_proj_W = (const float*)d_in[3];
    const float* conv_W    = (const float*)d_in[4];
    const float* conv_b    = (const float*)d_in[5];
    const float* x_proj_W  = (const float*)d_in[6];
    const float* dt_proj_W = (const float*)d_in[7];
    const float* dt_proj_b = (const float*)d_in[8];
    const float* A_log     = (const float*)d_in[9];
    const float* Dp        = (const float*)d_in[10];
    const float* out_proj_W= (const float*)d_in[11];
    const float* norm_W    = (const float*)d_in[12];
    const float* normf_W   = (const float*)d_in[13];
    const float* head_W    = (const float*)d_in[14];
    float* out = (float*)d_out;

    float* ws       = (float*)d_ws;
    // f32 region: x_ws + per-layer xdbl contiguous (single zero span), then xz, u.
    float* x_ws     = ws;                                        // M*384
    float* xdbl_ws  = x_ws    + (size_t)MROWS * D_MODEL;         // 4 * M*56
    float* xz_ws    = xdbl_ws + (size_t)N_LAYER * MROWS * XPROJ_N; // M*1536
    float* u_ws     = xz_ws   + (size_t)MROWS * 2 * D_INNER;     // M*768
    // bf16 region
    short* bf       = (short*)(u_ws + (size_t)MROWS * D_INNER);
    short* wbf_fc   = bf;
    short* wbf_in   = wbf_fc  + (size_t)D_MODEL * VOCAB;
    short* wbf_x    = wbf_in  + (size_t)N_LAYER * 2 * D_INNER * D_MODEL;
    short* wbf_out  = wbf_x   + (size_t)N_LAYER * XPROJ_N * D_INNER;
    short* wbf_head = wbf_out + (size_t)N_LAYER * D_MODEL * D_INNER;
    short* ids_bf   = wbf_head+ (size_t)FEAT * D_MODEL;
    short* ubf_ws   = ids_bf  + (size_t)MROWS * VOCAB;
    short* ybf_ws   = ubf_ws  + (size_t)MROWS * D_INNER;
    short* xnorm_bf = ybf_ws  + (size_t)MROWS * D_INNER;         // M*384 bf16

    const dim3 blk(256);
    const dim3 blk512(512);

    // --- one-shot cast to bf16 (weights + input_ids) + zero atomic dst buffers ---
    CastDesc cd;
    cd.src[0] = fc_W;       cd.dst[0] = wbf_fc;
    cd.src[1] = in_proj_W;  cd.dst[1] = wbf_in;
    cd.src[2] = x_proj_W;   cd.dst[2] = wbf_x;
    cd.src[3] = out_proj_W; cd.dst[3] = wbf_out;
    cd.src[4] = head_W;     cd.dst[4] = wbf_head;
    cd.src[5] = input_ids;  cd.dst[5] = ids_bf;
    unsigned c0 = (unsigned)(D_MODEL * VOCAB / 4);
    unsigned c1 = c0 + (unsigned)(N_LAYER * 2 * D_INNER * D_MODEL / 4);
    unsigned c2 = c1 + (unsigned)(N_LAYER * XPROJ_N * D_INNER / 4);
    unsigned c3 = c2 + (unsigned)(N_LAYER * D_MODEL * D_INNER / 4);
    unsigned c4 = c3 + (unsigned)(FEAT * D_MODEL / 4);
    unsigned c5 = c4 + (unsigned)(MROWS * VOCAB / 4);
    cd.cum[0] = c0; cd.cum[1] = c1; cd.cum[2] = c2;
    cd.cum[3] = c3; cd.cum[4] = c4; cd.cum[5] = c5;
    const unsigned zero4 = (unsigned)((MROWS * D_MODEL + N_LAYER * MROWS * XPROJ_N) / 4);
    cast_w_k<<<(c5 + zero4 + 255) / 256, blk, 0, stream>>>(cd, c5, (float4*)x_ws, zero4);

    // x = input_ids @ fc_W.T + fc_b   (A pre-cast bf16, split-K=7, atomic)
    mfma_gemm<1, true, false><<<dim3(D_MODEL / 64, MROWS / 64, 7), blk, 0, stream>>>(
        ids_bf, wbf_fc, fc_b, x_ws,
        MROWS, D_MODEL, VOCAB, VOCAB, D_MODEL, 256);

    for (int i = 0; i < N_LAYER; ++i) {
        float* xdbl_i = xdbl_ws + (size_t)i * MROWS * XPROJ_N;

        // xnorm = rmsnorm(x, norm_W) -> bf16 (one pass)
        rmsnorm_cast_k<<<MROWS * 8 / 256, blk, 0, stream>>>(
            x_ws, norm_W + i * D_MODEL, (unsigned*)xnorm_bf);

        // xz = xnorm @ in_proj_W.T  (pure ABF GEMM)
        mfma_gemm<0, false, false><<<dim3(2 * D_INNER / 64, MROWS / 64, 1), blk, 0, stream>>>(
            xnorm_bf, wbf_in + (size_t)i * 2 * D_INNER * D_MODEL,
            nullptr, xz_ws,
            MROWS, 2 * D_INNER, D_MODEL, D_MODEL, 2 * D_INNER, D_MODEL);

        // u = silu(conv(xz[:, :768]) + conv_b)  (f32 + bf16 copies)
        conv_silu_k<<<(MROWS * (D_INNER / 4) + 255) / 256, blk, 0, stream>>>(
            xz_ws, conv_W + (size_t)i * D_INNER * D_CONV, conv_b + i * D_INNER,
            u_ws, ubf_ws);

        // x_dbl = u @ x_proj_W[i].T  (A pre-cast bf16, N=56 guarded, split-K=12
        // -- r10: KC 128->64 doubles grid to 384 blocks; at split-K=6 only 192
        // blocks were resident on 256 CUs.  dst pre-zeroed once in cast_w_k.)
        mfma_gemm<0, true, true><<<dim3(1, MROWS / 64, 12), blk, 0, stream>>>(
            ubf_ws, wbf_x + (size_t)i * XPROJ_N * D_INNER,
            nullptr, xdbl_i,
            MROWS, XPROJ_N, D_INNER, D_INNER, XPROJ_N, 64);

        // fused: dt_proj+softplus -> carry-folded two-pass scan -> gate -> ybf
        scan_fused_k<<<dim3(D_INNER / DG, B_), blk512, 0, stream>>>(
            xdbl_i, u_ws, xz_ws,
            dt_proj_W + (size_t)i * D_INNER * DT_RANK, dt_proj_b + i * D_INNER,
            A_log + (size_t)i * D_INNER * N_STATE, Dp + i * D_INNER, ybf_ws);

        // x += ybf @ out_proj_W.T  (A pre-cast bf16 gated y, split-K=4 -- r10:
        // KC 384->192 doubles grid to 768 blocks (3/CU), atomic residual)
        mfma_gemm<0, true, false><<<dim3(D_MODEL / 64, MROWS / 64, 4), blk, 0, stream>>>(
            ybf_ws, wbf_out + (size_t)i * D_MODEL * D_INNER,
            nullptr, x_ws,
            MROWS, D_MODEL, D_INNER, D_INNER, D_MODEL, 192);
    }

    // out = rmsnorm(x, normf_W) @ head_W.T  (rmsnorm pre-pass + ABF)
    rmsnorm_cast_k<<<MROWS * 8 / 256, blk, 0, stream>>>(
        x_ws, normf_W, (unsigned*)xnorm_bf);
    mfma_gemm<0, false, false><<<dim3(FEAT / 64, MROWS / 64, 1), blk, 0, stream>>>(
        xnorm_bf, wbf_head, nullptr, out,
        MROWS, FEAT, D_MODEL, D_MODEL, FEAT, D_MODEL);
}

// Round 11
// 432.288 us; speedup vs baseline: 1.0515x; 1.0515x over previous
//
#include <hip/hip_runtime.h>
#include <math.h>

// Problem dims
#define B_ 4
#define L_ 512
#define MROWS 2048
#define D_MODEL 384
#define N_LAYER 4
#define D_INNER 768
#define N_STATE 16
#define DT_RANK 24
#define D_CONV 4
#define VOCAB 1544
#define FEAT 1536
#define XPROJ_N 56
#define NCH 16              // scan chunks per batch (L/32)
#define SCH 32              // scan chunk length
#define DG 2                // d-channels per scan block

typedef __attribute__((ext_vector_type(8))) short short8;
typedef __attribute__((ext_vector_type(4))) float floatx4;

__device__ __forceinline__ float softplus_f(float x) { return x > 20.f ? x : log1pf(expf(x)); }
__device__ __forceinline__ float silu_f(float x) { return x / (1.f + __expf(-x)); }

// f32 -> bf16 (RNE), two packed into one u32
__device__ __forceinline__ unsigned pack2bf(float x, float y) {
    unsigned ux = __float_as_uint(x); ux = (ux + 0x7FFFu + ((ux >> 16) & 1u)) >> 16;
    unsigned uy = __float_as_uint(y); uy = (uy + 0x7FFFu + ((uy >> 16) & 1u)) >> 16;
    return ux | (uy << 16);
}

// DPP row-rotate add: x + (x ror N within each 16-lane row). After ror
// 8,4,2,1 every lane holds the full 16-sum.
template <int CTRL>
__device__ __forceinline__ float dpp_radd(float x) {
    int r = __builtin_amdgcn_update_dpp(0, __float_as_int(x), CTRL, 0xf, 0xf, true);
    return x + __int_as_float(r);
}

// Wave-local LDS fence: producer and consumer are the SAME wave (cross-lane
// ok) -- s_waitcnt makes the wave's own ds_writes visible, wave_barrier pins
// ordering. Replaces __syncthreads where no cross-wave data flows.
__device__ __forceinline__ void wave_lds_fence() {
    asm volatile("s_waitcnt lgkmcnt(0)" ::: "memory");
    __builtin_amdgcn_wave_barrier();
}

__device__ __forceinline__ short8 ld8h_guard(const short* __restrict__ p, int k, int ke) {
    if (k + 7 < ke) return *(const short8*)(p + k);
    short8 r = {0, 0, 0, 0, 0, 0, 0, 0};
#pragma unroll
    for (int j = 0; j < 8; ++j)
        if (k + j < ke) r[j] = p[k + j];
    return r;
}

// ---------------------------------------------------------------------------
// One-shot weight/input cast f32 -> bf16 + grid-stride zeroing of atomic dsts.
// ---------------------------------------------------------------------------
struct CastDesc {
    const float* src[6];
    short*       dst[6];
    unsigned     cum[6];   // exclusive prefix ends, in float4 units
};

__global__ __launch_bounds__(256) void cast_w_k(CastDesc cd, unsigned total4,
                                                float4* __restrict__ zb, unsigned z4)
{
    unsigned i = blockIdx.x * 256 + threadIdx.x;
    if (i < total4) {
        int s = 0;
#pragma unroll
        for (int j = 0; j < 5; ++j)
            if (i >= cd.cum[j] && s == j) s = j + 1;
        unsigned off = i - (s ? cd.cum[s - 1] : 0u);
        float4 v = ((const float4*)cd.src[s])[off];
        uint2 pk;
        pk.x = pack2bf(v.x, v.y);
        pk.y = pack2bf(v.z, v.w);
        ((uint2*)cd.dst[s])[off] = pk;
    } else {
        unsigned zi = i - total4;
        if (zi < z4) zb[zi] = make_float4(0.f, 0.f, 0.f, 0.f);
    }
}

// ---------------------------------------------------------------------------
// RMSNorm + weight scale + bf16 cast, one pass.  8 lanes per row.
// ---------------------------------------------------------------------------
__global__ __launch_bounds__(256) void rmsnorm_cast_k(
    const float* __restrict__ x, const float* __restrict__ nw,
    unsigned* __restrict__ outp)
{
    const int idx = blockIdx.x * 256 + threadIdx.x;
    const int row = idx >> 3, q = idx & 7;
    const float* xr = x + (size_t)row * D_MODEL + q * 48;
    float4 v[12];
    float s = 0.f;
#pragma unroll
    for (int i = 0; i < 12; ++i) {
        v[i] = *(const float4*)(xr + i * 4);
        s += v[i].x * v[i].x + v[i].y * v[i].y + v[i].z * v[i].z + v[i].w * v[i].w;
    }
    s += __shfl_xor(s, 1, 64);
    s += __shfl_xor(s, 2, 64);
    s += __shfl_xor(s, 4, 64);
    const float sc = rsqrtf(s / (float)D_MODEL + 1e-5f);
    unsigned* op = outp + ((size_t)row * D_MODEL + q * 48) / 2;
#pragma unroll
    for (int i = 0; i < 12; ++i) {
        float4 wv = *(const float4*)(nw + q * 48 + i * 4);
        op[i * 2]     = pack2bf(v[i].x * (sc * wv.x), v[i].y * (sc * wv.y));
        op[i * 2 + 1] = pack2bf(v[i].z * (sc * wv.z), v[i].w * (sc * wv.w));
    }
}

// ---------------------------------------------------------------------------
// MFMA bf16 GEMM: C[m,n] (+)= sum_k A[m,k]*W[n,k].  A and W pre-cast bf16.
// Pipelined K-loop: stage(k+1) -> prefetch(k+2) -> MFMA(k) -> barrier.
// EPI: 0 none, 1 +bias(z==0 if ATOMIC), 2 softplus+bias.
// ---------------------------------------------------------------------------
#define ASTR 40

template <int EPI, bool ATOMIC, bool NG>
__global__ __launch_bounds__(256) void mfma_gemm(
    const short* __restrict__ Abf,
    const short* __restrict__ Wb,
    const float* __restrict__ bias,
    float* __restrict__ C, int M, int N, int K, int lda, int ldc, int KC)
{
    __shared__ short As[2][64 * ASTR];
    __shared__ short Ws[2][64 * ASTR];

    const int t  = threadIdx.x;
    const int m0 = blockIdx.y * 64;
    const int n0 = blockIdx.x * 64;
    const int ks = blockIdx.z * KC;
    const int ke = min(K, ks + KC);

    const int srow = t >> 2;           // 0..63
    const int sseg = (t & 3) * 8;      // 0,8,16,24

    short8 ra8, rw8;

    auto prefetch = [&](int k0) {
        ra8 = ld8h_guard(Abf + (size_t)(m0 + srow) * lda, k0 + sseg, ke);
        if (!NG || (n0 + srow) < N) {
            rw8 = ld8h_guard(Wb + (size_t)(n0 + srow) * (size_t)K, k0 + sseg, ke);
        } else {
            rw8 = (short8){0, 0, 0, 0, 0, 0, 0, 0};
        }
    };

    auto stage = [&](int p) {
        *(short8*)&As[p][srow * ASTR + sseg] = ra8;
        *(short8*)&Ws[p][srow * ASTR + sseg] = rw8;
    };

    prefetch(ks);
    stage(0);
    if (ks + 32 < ke) prefetch(ks + 32);   // loads for iter 2 in flight across barrier
    __syncthreads();

    floatx4 acc[2][2];
#pragma unroll
    for (int i = 0; i < 2; ++i)
#pragma unroll
        for (int j = 0; j < 2; ++j) acc[i][j] = (floatx4){0.f, 0.f, 0.f, 0.f};

    const int w    = t >> 6;
    const int lane = t & 63;
    const int quad = lane >> 4;
    const int lm   = lane & 15;
    const int aoff = ((w >> 1) * 32 + lm) * ASTR + quad * 8;
    const int boff = ((w & 1) * 32 + lm) * ASTR + quad * 8;

    int p = 0;
    for (int k0 = ks; k0 < ke; k0 += 32) {
        const bool more = (k0 + 32 < ke);
        if (more) {
            stage(p ^ 1);                       // consumes loads issued 1 iter ago
            if (k0 + 64 < ke) prefetch(k0 + 64); // issue 2 iters ahead
        }
        short8 a0 = *(const short8*)&As[p][aoff];
        short8 a1 = *(const short8*)&As[p][aoff + 16 * ASTR];
        short8 b0 = *(const short8*)&Ws[p][boff];
        short8 b1 = *(const short8*)&Ws[p][boff + 16 * ASTR];
        acc[0][0] = __builtin_amdgcn_mfma_f32_16x16x32_bf16(a0, b0, acc[0][0], 0, 0, 0);
        acc[0][1] = __builtin_amdgcn_mfma_f32_16x16x32_bf16(a0, b1, acc[0][1], 0, 0, 0);
        acc[1][0] = __builtin_amdgcn_mfma_f32_16x16x32_bf16(a1, b0, acc[1][0], 0, 0, 0);
        acc[1][1] = __builtin_amdgcn_mfma_f32_16x16x32_bf16(a1, b1, acc[1][1], 0, 0, 0);
        if (more) {
            __syncthreads();
            p ^= 1;
        }
    }

    const int rbase = m0 + (w >> 1) * 32 + quad * 4;
    const int cbase = n0 + (w & 1) * 32 + lm;
#pragma unroll
    for (int mt = 0; mt < 2; ++mt)
#pragma unroll
        for (int nt = 0; nt < 2; ++nt) {
            const int gc = cbase + nt * 16;
            if (NG && gc >= N) continue;
#pragma unroll
            for (int r = 0; r < 4; ++r) {
                const size_t gr = rbase + mt * 16 + r;
                float v = acc[mt][nt][r];
                if (ATOMIC) {
                    if (EPI == 1 && blockIdx.z == 0) v += bias[gc];
                    atomicAdd(&C[gr * ldc + gc], v);
                } else {
                    if (EPI == 1) v += bias[gc];
                    if (EPI == 2) v = softplus_f(v + bias[gc]);
                    C[gr * ldc + gc] = v;
                }
            }
        }
}

// ---------------------------------------------------------------------------
// Depthwise causal conv (width 4) + bias + SiLU; writes u (f32) and u_bf.
// (r6 form -- coalesced: consecutive threads = consecutive d within a row.
// r7/r9 fusion attempts both lost to this plain version.)
// ---------------------------------------------------------------------------
__global__ __launch_bounds__(256) void conv_silu_k(
    const float* __restrict__ xz, const float* __restrict__ w,
    const float* __restrict__ cb, float* __restrict__ u, short* __restrict__ ubf)
{
    int idx = blockIdx.x * 256 + threadIdx.x;
    if (idx >= MROWS * (D_INNER / 4)) return;
    int dq = idx % (D_INNER / 4);
    int m  = idx / (D_INNER / 4);
    int d0 = dq * 4;
    int b = m / L_, l = m % L_;
    float4 wq[4];
#pragma unroll
    for (int j = 0; j < 4; ++j) wq[j] = *(const float4*)(w + (d0 + j) * D_CONV);
    float acc[4];
#pragma unroll
    for (int j = 0; j < 4; ++j) acc[j] = cb[d0 + j];
#pragma unroll
    for (int tt = 0; tt < 4; ++tt) {
        int ll = l - 3 + tt;
        if (ll >= 0) {
            float4 xv = *(const float4*)(xz + (size_t)(b * L_ + ll) * (2 * D_INNER) + d0);
            acc[0] = fmaf(xv.x, ((const float*)&wq[0])[tt], acc[0]);
            acc[1] = fmaf(xv.y, ((const float*)&wq[1])[tt], acc[1]);
            acc[2] = fmaf(xv.z, ((const float*)&wq[2])[tt], acc[2]);
            acc[3] = fmaf(xv.w, ((const float*)&wq[3])[tt], acc[3]);
        }
    }
    float4 o = make_float4(silu_f(acc[0]), silu_f(acc[1]), silu_f(acc[2]), silu_f(acc[3]));
    *(float4*)(u + (size_t)m * D_INNER + d0) = o;
    uint2 pk;
    pk.x = pack2bf(o.x, o.y);
    pk.y = pack2bf(o.z, o.w);
    *(uint2*)(ubf + (size_t)m * D_INNER + d0) = pk;
}

// ---------------------------------------------------------------------------
// Fused selective scan (exact r6 form -- best measured across r6..r10).
// Carry-folded two-pass:
//   phase 0: row-task dt-proj (each thread one row, both channels), {delta,u}
//            packed float2 in LDS, early xz gate load
//   pass 1 : P/H only, no reduce; P = exp(Av*sum(dv))
//   barrier; pass-2 group-0 B/C loads issued before it
//   carry  : fixed-unroll masked fold (15 batched LDS loads)
//   pass 2 : full recurrence from h=hs (B/C reload, 8-deep prefetch)
//   phase C: gate + bf16 emit
// ---------------------------------------------------------------------------
__global__ __launch_bounds__(512, 4) void scan_fused_k(
    const float* __restrict__ xdbl, const float* __restrict__ u,
    const float* __restrict__ xz,
    const float* __restrict__ dtW, const float* __restrict__ dtb,
    const float* __restrict__ A_log, const float* __restrict__ Dp,
    short* __restrict__ ybf)
{
    __shared__ __align__(16) float2 sdu[NCH][SCH][DG];     // {delta,u} 8KB
    __shared__ __align__(16) float  sy[NCH][SCH][DG];      // 4KB
    __shared__ __align__(16) float2 sPH[NCH][DG][16];      // {P,H} 4KB

    const int t  = threadIdx.x;
    const int w  = t >> 6;          // wave 0..7
    const int l  = t & 63;
    const int ch = l >> 5;          // 0..1 -> which of the wave's two chunks
    const int c  = w * 2 + ch;      // chunk 0..15
    const int dl = (l >> 4) & 1;    // channel within block
    const int n  = l & 15;          // state index
    // XCD-chunked swizzle (bijective, 384 = 8 * 48): adjacent d-groups share
    // cache lines of u/xz/ybf -> keep them on one XCD (r1: FETCH 51->8MB).
    const int bx  = blockIdx.x;
    const int dgi = (bx & 7) * (D_INNER / DG / 8) + (bx >> 3);
    const int d0 = dgi * DG;
    const int d  = d0 + dl;
    const int b  = blockIdx.y;

    // row-task mapping (each thread owns one global row)
    const int tc = t >> 5, tj = t & 31;          // tc in {2w, 2w+1} -> wave-private
    const size_t trow = (size_t)b * L_ + t;

    // ---- phase 0: wave-private staging ----
    // early-issue phase-C gate load (consumed ~3000cy later)
    float2 rv  = *(const float2*)(xz + trow * (2 * D_INNER) + D_INNER + d0);
    float2 uv2 = *(const float2*)(u + trow * D_INNER + d0);

    // delta for BOTH channels of this thread's row; dtW/dtb are block-uniform
    {
        const float* wd = dtW + (size_t)d0 * DT_RANK;
        const float* xr = xdbl + trow * XPROJ_N;
        float acc0 = dtb[d0];
        float acc1 = dtb[d0 + 1];
#pragma unroll
        for (int q = 0; q < 6; ++q) {
            float4 xv = *(const float4*)(xr + q * 4);
            float4 w0 = *(const float4*)(wd + q * 4);
            float4 w1 = *(const float4*)(wd + DT_RANK + q * 4);
            acc0 = fmaf(xv.x, w0.x, acc0); acc0 = fmaf(xv.y, w0.y, acc0);
            acc0 = fmaf(xv.z, w0.z, acc0); acc0 = fmaf(xv.w, w0.w, acc0);
            acc1 = fmaf(xv.x, w1.x, acc1); acc1 = fmaf(xv.y, w1.y, acc1);
            acc1 = fmaf(xv.z, w1.z, acc1); acc1 = fmaf(xv.w, w1.w, acc1);
        }
        float4 pk = make_float4(softplus_f(acc0), uv2.x, softplus_f(acc1), uv2.y);
        *(float4*)&sdu[tc][tj][0] = pk;   // one ds_write_b128
    }
    wave_lds_fence();   // sdu for chunks {2w,2w+1} produced+consumed by wave w

    const float Av = -expf(A_log[d * N_STATE + n]);
    const float Dd = Dp[d];
    const float* xbn = xdbl + ((size_t)b * L_ + c * SCH) * XPROJ_N + DT_RANK + n;

    // ---- pass 1: chunk-local end-state H and decay product P (no reduce) ----
    {
        float h = 0.f, sdv = 0.f;
        float rB[8];
#pragma unroll
        for (int q = 0; q < 8; ++q) rB[q] = xbn[q * XPROJ_N];
#pragma unroll
        for (int g = 0; g < SCH / 8; ++g) {
            float nB[8];
            if (g + 1 < SCH / 8) {
#pragma unroll
                for (int q = 0; q < 8; ++q) nB[q] = xbn[(g * 8 + 8 + q) * XPROJ_N];
            }
#pragma unroll
            for (int q = 0; q < 8; ++q) {
                const int j = g * 8 + q;
                float2 du = *(const float2*)&sdu[c][j][dl];
                float e  = __expf(du.x * Av);
                h = fmaf(e, h, du.x * du.y * rB[q]);
                sdv += du.x;
            }
#pragma unroll
            for (int q = 0; q < 8; ++q) rB[q] = nB[q];
        }
        float2 ph;
        ph.x = __expf(sdv * Av);   // prod of exps = exp of sum
        ph.y = h;
        *(float2*)&sPH[c][dl][n] = ph;
    }

    // issue pass-2 group-0 B/C loads BEFORE the barrier (latency cover)
    float rB[8], rC[8];
#pragma unroll
    for (int q = 0; q < 8; ++q) {
        rB[q] = xbn[q * XPROJ_N];
        rC[q] = xbn[q * XPROJ_N + N_STATE];
    }
    __syncthreads();    // the only cross-wave exchange (sPH)

    // ---- carry-in: fixed-unroll masked fold (all 15 loads batch) ----
    float hs = 0.f;
#pragma unroll
    for (int s = 0; s < NCH - 1; ++s) {
        float2 ph = *(const float2*)&sPH[s][dl][n];
        const bool m = s < c;
        hs = fmaf(m ? ph.x : 1.f, hs, m ? ph.y : 0.f);
    }

    // ---- pass 2: full recurrence from h=hs; y is final directly ----
    {
        float h = hs;
#pragma unroll
        for (int g = 0; g < SCH / 8; ++g) {
            float nB[8], nC[8];
            if (g + 1 < SCH / 8) {
#pragma unroll
                for (int q = 0; q < 8; ++q) {
                    nB[q] = xbn[(g * 8 + 8 + q) * XPROJ_N];
                    nC[q] = xbn[(g * 8 + 8 + q) * XPROJ_N + N_STATE];
                }
            }
#pragma unroll
            for (int q = 0; q < 8; ++q) {
                const int j = g * 8 + q;
                float2 du = *(const float2*)&sdu[c][j][dl];
                float e  = __expf(du.x * Av);
                h = fmaf(e, h, du.x * du.y * rB[q]);
                float p = h * rC[q];
                p = dpp_radd<0x128>(p);
                p = dpp_radd<0x124>(p);
                p = dpp_radd<0x122>(p);
                p = dpp_radd<0x121>(p);
                if (n == 0) sy[c][j][dl] = fmaf(du.y, Dd, p);
            }
#pragma unroll
            for (int q = 0; q < 8; ++q) { rB[q] = nB[q]; rC[q] = nC[q]; }
        }
    }
    wave_lds_fence();   // sy for chunks {2w,2w+1} is wave-private

    // ---- phase C: gate with silu(res) and emit bf16 ----
    {
        float2 yv = *(const float2*)&sy[tc][tj][0];
        float o0 = yv.x * silu_f(rv.x);
        float o1 = yv.y * silu_f(rv.y);
        *(unsigned*)(ybf + trow * D_INNER + d0) = pack2bf(o0, o1);
    }
}

// ---------------------------------------------------------------------------
extern "C" void kernel_launch(void* const* d_in, const int* in_sizes, int n_in,
                              void* d_out, int out_size, void* d_ws, size_t ws_size,
                              hipStream_t stream)
{
    const float* input_ids = (const float*)d_in[0];
    const float* fc_W      = (const float*)d_in[1];
    const float* fc_b      = (const float*)d_in[2];
    const float* in_proj_W = (const float*)d_in[3];
    const float* conv_W    = (const float*)d_in[4];
    const float* conv_b    = (const float*)d_in[5];
    const float* x_proj_W  = (const float*)d_in[6];
    const float* dt_proj_W = (const float*)d_in[7];
    const float* dt_proj_b = (const float*)d_in[8];
    const float* A_log     = (const float*)d_in[9];
    const float* Dp        = (const float*)d_in[10];
    const float* out_proj_W= (const float*)d_in[11];
    const float* norm_W    = (const float*)d_in[12];
    const float* normf_W   = (const float*)d_in[13];
    const float* head_W    = (const float*)d_in[14];
    float* out = (float*)d_out;

    float* ws       = (float*)d_ws;
    // f32 region: x_ws + per-layer xdbl contiguous (single zero span), then xz, u.
    float* x_ws     = ws;                                        // M*384
    float* xdbl_ws  = x_ws    + (size_t)MROWS * D_MODEL;         // 4 * M*56
    float* xz_ws    = xdbl_ws + (size_t)N_LAYER * MROWS * XPROJ_N; // M*1536
    float* u_ws     = xz_ws   + (size_t)MROWS * 2 * D_INNER;     // M*768
    // bf16 region
    short* bf       = (short*)(u_ws + (size_t)MROWS * D_INNER);
    short* wbf_fc   = bf;
    short* wbf_in   = wbf_fc  + (size_t)D_MODEL * VOCAB;
    short* wbf_x    = wbf_in  + (size_t)N_LAYER * 2 * D_INNER * D_MODEL;
    short* wbf_out  = wbf_x   + (size_t)N_LAYER * XPROJ_N * D_INNER;
    short* wbf_head = wbf_out + (size_t)N_LAYER * D_MODEL * D_INNER;
    short* ids_bf   = wbf_head+ (size_t)FEAT * D_MODEL;
    short* ubf_ws   = ids_bf  + (size_t)MROWS * VOCAB;
    short* ybf_ws   = ubf_ws  + (size_t)MROWS * D_INNER;
    short* xnorm_bf = ybf_ws  + (size_t)MROWS * D_INNER;         // M*384 bf16

    const dim3 blk(256);
    const dim3 blk512(512);

    // --- one-shot cast to bf16 (weights + input_ids) + zero atomic dst buffers ---
    CastDesc cd;
    cd.src[0] = fc_W;       cd.dst[0] = wbf_fc;
    cd.src[1] = in_proj_W;  cd.dst[1] = wbf_in;
    cd.src[2] = x_proj_W;   cd.dst[2] = wbf_x;
    cd.src[3] = out_proj_W; cd.dst[3] = wbf_out;
    cd.src[4] = head_W;     cd.dst[4] = wbf_head;
    cd.src[5] = input_ids;  cd.dst[5] = ids_bf;
    unsigned c0 = (unsigned)(D_MODEL * VOCAB / 4);
    unsigned c1 = c0 + (unsigned)(N_LAYER * 2 * D_INNER * D_MODEL / 4);
    unsigned c2 = c1 + (unsigned)(N_LAYER * XPROJ_N * D_INNER / 4);
    unsigned c3 = c2 + (unsigned)(N_LAYER * D_MODEL * D_INNER / 4);
    unsigned c4 = c3 + (unsigned)(FEAT * D_MODEL / 4);
    unsigned c5 = c4 + (unsigned)(MROWS * VOCAB / 4);
    cd.cum[0] = c0; cd.cum[1] = c1; cd.cum[2] = c2;
    cd.cum[3] = c3; cd.cum[4] = c4; cd.cum[5] = c5;
    const unsigned zero4 = (unsigned)((MROWS * D_MODEL + N_LAYER * MROWS * XPROJ_N) / 4);
    cast_w_k<<<(c5 + zero4 + 255) / 256, blk, 0, stream>>>(cd, c5, (float4*)x_ws, zero4);

    // x = input_ids @ fc_W.T + fc_b   (A pre-cast bf16, split-K=7, atomic)
    mfma_gemm<1, true, false><<<dim3(D_MODEL / 64, MROWS / 64, 7), blk, 0, stream>>>(
        ids_bf, wbf_fc, fc_b, x_ws,
        MROWS, D_MODEL, VOCAB, VOCAB, D_MODEL, 256);

    for (int i = 0; i < N_LAYER; ++i) {
        float* xdbl_i = xdbl_ws + (size_t)i * MROWS * XPROJ_N;

        // xnorm = rmsnorm(x, norm_W) -> bf16 (one pass)
        rmsnorm_cast_k<<<MROWS * 8 / 256, blk, 0, stream>>>(
            x_ws, norm_W + i * D_MODEL, (unsigned*)xnorm_bf);

        // xz = xnorm @ in_proj_W.T  (pure ABF GEMM)
        mfma_gemm<0, false, false><<<dim3(2 * D_INNER / 64, MROWS / 64, 1), blk, 0, stream>>>(
            xnorm_bf, wbf_in + (size_t)i * 2 * D_INNER * D_MODEL,
            nullptr, xz_ws,
            MROWS, 2 * D_INNER, D_MODEL, D_MODEL, 2 * D_INNER, D_MODEL);

        // u = silu(conv(xz[:, :768]) + conv_b)  (f32 + bf16 copies)
        conv_silu_k<<<(MROWS * (D_INNER / 4) + 255) / 256, blk, 0, stream>>>(
            xz_ws, conv_W + (size_t)i * D_INNER * D_CONV, conv_b + i * D_INNER,
            u_ws, ubf_ws);

        // x_dbl = u @ x_proj_W[i].T  (A pre-cast bf16, N=56 guarded, split-K=6,
        // KC=128 -- r10's split-K=12 doubled atomics and regressed; reverted.
        // dst pre-zeroed once in cast_w_k -- per-layer buffer)
        mfma_gemm<0, true, true><<<dim3(1, MROWS / 64, 6), blk, 0, stream>>>(
            ubf_ws, wbf_x + (size_t)i * XPROJ_N * D_INNER,
            nullptr, xdbl_i,
            MROWS, XPROJ_N, D_INNER, D_INNER, XPROJ_N, 128);

        // fused: dt_proj+softplus -> carry-folded two-pass scan -> gate -> ybf
        scan_fused_k<<<dim3(D_INNER / DG, B_), blk512, 0, stream>>>(
            xdbl_i, u_ws, xz_ws,
            dt_proj_W + (size_t)i * D_INNER * DT_RANK, dt_proj_b + i * D_INNER,
            A_log + (size_t)i * D_INNER * N_STATE, Dp + i * D_INNER, ybf_ws);

        // x += ybf @ out_proj_W.T  (A pre-cast bf16 gated y, split-K=2, KC=384
        // -- r10's split-K=4 regressed via atomic contention; reverted)
        mfma_gemm<0, true, false><<<dim3(D_MODEL / 64, MROWS / 64, 2), blk, 0, stream>>>(
            ybf_ws, wbf_out + (size_t)i * D_MODEL * D_INNER,
            nullptr, x_ws,
            MROWS, D_MODEL, D_INNER, D_INNER, D_MODEL, 384);
    }

    // out = rmsnorm(x, normf_W) @ head_W.T  (rmsnorm pre-pass + ABF)
    rmsnorm_cast_k<<<MROWS * 8 / 256, blk, 0, stream>>>(
        x_ws, normf_W, (unsigned*)xnorm_bf);
    mfma_gemm<0, false, false><<<dim3(FEAT / 64, MROWS / 64, 1), blk, 0, stream>>>(
        xnorm_bf, wbf_head, nullptr, out,
        MROWS, FEAT, D_MODEL, D_MODEL, FEAT, D_MODEL);
}